// Round 12
// baseline (201.425 us; speedup 1.0000x reference)
//
#include <hip/hip_runtime.h>
#include <hip/hip_bf16.h>
#include <stdint.h>

#define NTOK 4096
#define DM   512
#define HD   2048
#define NE   8

typedef __bf16 bf16x8 __attribute__((ext_vector_type(8)));
typedef float  f32x4  __attribute__((ext_vector_type(4)));

__device__ __forceinline__ unsigned short f2bf(float f) {
  unsigned int u = __float_as_uint(f);
  u += 0x7FFF + ((u >> 16) & 1);   // RTNE
  return (unsigned short)(u >> 16);
}

__device__ __forceinline__ float gelu_fast(float x) {
  float s = 1.5957691216f * (x + 0.044715f * x * x * x);
  return x / (1.f + __expf(-s));
}

__device__ __forceinline__ void gload_lds16(const void* g, void* l) {
  __builtin_amdgcn_global_load_lds(
      (__attribute__((address_space(1))) const void*)g,
      (__attribute__((address_space(3))) void*)l,
      16, 0, 0);
}

// ---------- W[e][K][N] fp32 -> WT[e][N][K] bf16 transpose (device body) ----------
template<int K, int N>
__device__ __forceinline__ void transw_dev(
    const float* __restrict__ in, unsigned short* __restrict__ out,
    int bid, int t, float (*tile)[33]) {
  const int tpe = (K / 32) * (N / 32);
  int e   = bid / tpe;
  int rem = bid % tpe;
  int kt  = rem / (N / 32), nt = rem % (N / 32);
  int tx  = t & 31, ty = t >> 5;
  const float* src = in + ((size_t)e * K + kt * 32) * N + (size_t)nt * 32;
  #pragma unroll
  for (int i = 0; i < 4; i++) {
    int r = ty + i * 8;
    tile[r][tx] = src[(size_t)r * N + tx];
  }
  __syncthreads();
  unsigned short* dst = out + ((size_t)e * N + nt * 32) * K + (size_t)kt * 32;
  #pragma unroll
  for (int i = 0; i < 4; i++) {
    int rr = ty + i * 8;
    dst[(size_t)rr * K + tx] = f2bf(tile[tx][rr]);
  }
}

// ---------- fused prep: convx | transw1 | transw2 | gate (independent, 1 dispatch) ----------
// Block ranges: [0,1024) convx | [1024,9216) transw1 (8192) | [9216,17408) transw2 (8192)
// | [17408,18432) gate. (R11 bug: transposes need 8*(K/32)*(N/32) = 8192 blocks EACH.)
__global__ __launch_bounds__(256) void prep_kernel(
    const float* __restrict__ inp, const float* __restrict__ w1,
    const float* __restrict__ w2, const float* __restrict__ gw,
    const float* __restrict__ gb, unsigned short* __restrict__ Xb,
    unsigned short* __restrict__ W1T, unsigned short* __restrict__ W2T,
    int* __restrict__ eidx, float* __restrict__ wgtA) {
  __shared__ float tile[32][33];
  const int b = blockIdx.x;
  const int t = threadIdx.x;

  if (b < 1024) {                     // ---- convx: X fp32 -> bf16 (262144 x8-groups)
    int i = b * 256 + t;
    const f32x4* p = (const f32x4*)(inp + (size_t)i * 8);
    f32x4 v0 = p[0], v1 = p[1];
    union { unsigned short s[8]; uint4 u; } o;
    #pragma unroll
    for (int j = 0; j < 4; j++) { o.s[j] = f2bf(v0[j]); o.s[4 + j] = f2bf(v1[j]); }
    *(uint4*)(Xb + (size_t)i * 8) = o.u;
  } else if (b < 9216) {              // ---- transpose w1 [8][512][2048] -> [8][2048][512]
    transw_dev<DM, HD>(w1, W1T, b - 1024, t, tile);
  } else if (b < 17408) {             // ---- transpose w2 [8][2048][512] -> [8][512][2048]
    transw_dev<HD, DM>(w2, W2T, b - 9216, t, tile);
  } else {                            // ---- gate: logits, top-2, softmax (no atomics)
    int tok = (b - 17408) * 4 + (t >> 6);
    int l   = t & 63;
    const float* x = inp + (size_t)tok * DM;
    float acc[NE];
    #pragma unroll
    for (int e = 0; e < NE; e++) acc[e] = 0.f;
    #pragma unroll
    for (int j = 0; j < DM / 64; j++) {
      int d = j * 64 + l;
      float xv = x[d];
      const float* g = gw + (size_t)d * NE;
      #pragma unroll
      for (int e = 0; e < NE; e++) acc[e] += xv * g[e];
    }
    #pragma unroll
    for (int off = 32; off >= 1; off >>= 1) {
      #pragma unroll
      for (int e = 0; e < NE; e++) acc[e] += __shfl_xor(acc[e], off, 64);
    }
    if (l == 0) {
      float lg[NE];
      #pragma unroll
      for (int e = 0; e < NE; e++) lg[e] = acc[e] + gb[e];
      int i0 = 0;
      #pragma unroll
      for (int e = 1; e < NE; e++) if (lg[e] > lg[i0]) i0 = e;
      int i1 = (i0 == 0) ? 1 : 0;
      #pragma unroll
      for (int e = 0; e < NE; e++) if (e != i0 && lg[e] > lg[i1]) i1 = e;
      float ev = expf(lg[i1] - lg[i0]);
      float w0 = 1.f / (1.f + ev);
      float w1s = ev * w0;
      wgtA[tok * 2]     = w0;
      wgtA[tok * 2 + 1] = w1s;
      eidx[tok * 2]     = i0;
      eidx[tok * 2 + 1] = i1;
    }
  }
}

// ---------- build per-expert entry lists: 1 block per expert, ballot prefix scan ----------
__global__ __launch_bounds__(256) void build_lists(
    const int* __restrict__ eidx, int* __restrict__ lists,
    int* __restrict__ counts) {
  __shared__ int wsums[4];
  __shared__ int base;
  const int e = blockIdx.x;
  const int t = threadIdx.x;
  const int lane = t & 63, w = t >> 6;
  if (t == 0) base = 0;
  __syncthreads();
  for (int it = 0; it < 2 * NTOK / 256; ++it) {
    int i = it * 256 + t;
    int match = (eidx[i] == e) ? 1 : 0;
    unsigned long long b = __ballot(match);
    int wsum = __popcll(b);
    int lpre = __popcll(b & ((1ull << lane) - 1ull));
    if (lane == 0) wsums[w] = wsum;
    __syncthreads();
    int wpre = 0;
    #pragma unroll
    for (int k = 0; k < 4; k++) if (k < w) wpre += wsums[k];
    int tot = wsums[0] + wsums[1] + wsums[2] + wsums[3];
    if (match) lists[e * NTOK + base + wpre + lpre] = i;
    __syncthreads();
    if (t == 0) base += tot;
    __syncthreads();
  }
  if (t == 0) counts[e] = base;
}

// ---------- gathered GEMM: 128x128 tile, BK=128, 4 waves, 16x16x32 bf16 MFMA ----------
// R10 structure (expert->XCD pinning, 2-barrier loop, T2 swizzle) + KSPLIT for the
// L2 layer: 4 K-chunks of 512 -> 4x blocks -> restores a 2nd resident block per CU
// so stage latency of one block hides under compute of the other.
template<int KDIM, int NDIM, bool IS_L1, int KSPLIT>
__global__ __launch_bounds__(256) void moe_gemm(
    const unsigned short* __restrict__ A,
    const unsigned short* __restrict__ WT,     // [E][NDIM][KDIM] bf16
    const float* __restrict__ bias,            // [E][NDIM]
    const int* __restrict__ lists,             // [E][NTOK]
    const int* __restrict__ counts,            // [E]
    const float* __restrict__ wgtA,            // [2*NTOK]
    unsigned short* __restrict__ Hout,
    float* __restrict__ Out) {
  __shared__ unsigned short ldsA[128 * 128];   // 32 KiB
  __shared__ unsigned short ldsB[128 * 128];   // 32 KiB
  __shared__ int ldsE[128];

  const int CT  = NDIM / 128;
  const int e   = blockIdx.x & 7;              // expert == XCD (HW round-robin, m09)
  const int idx = blockIdx.x >> 3;
  const int rt  = idx / (KSPLIT * CT);
  const int r2  = idx % (KSPLIT * CT);
  const int ks  = r2 / CT;
  const int ct  = r2 % CT;
  const int cnt = counts[e];
  if (rt * 128 >= cnt) return;

  const int t = threadIdx.x;
  if (t < 128) {
    int rg = rt * 128 + t;
    ldsE[t] = lists[e * NTOK + (rg < cnt ? rg : cnt - 1)];
  }
  __syncthreads();

  const int lane = t & 63;
  const int wid  = t >> 6;
  const int wr = wid >> 1, wc = wid & 1;
  const int rowsel = t >> 4;                   // 0..15: row within each 16-row issue group
  const int chunk  = (t & 15) ^ (rowsel & 7);  // inverse-swizzled 16B source chunk

  const int KCH = KDIM / KSPLIT;               // 512 for both layers
  const unsigned short* aptr[8];
  const unsigned short* bptr[8];
  #pragma unroll
  for (int i = 0; i < 8; i++) {
    int rl = i * 16 + rowsel;
    int entry = ldsE[rl];
    long arow = IS_L1 ? (entry >> 1) : entry;
    aptr[i] = A + arow * (long)KDIM + ks * KCH + chunk * 8;
    bptr[i] = WT + ((long)e * NDIM + ct * 128 + rl) * KDIM + ks * KCH + chunk * 8;
  }

  f32x4 acc[4][4] = {};

  const int NKT = KCH / 128;                   // 4 for both layers
  for (int kt = 0; kt < NKT; ++kt) {
    #pragma unroll
    for (int i = 0; i < 8; i++) {
      gload_lds16(aptr[i] + kt * 128, (char*)ldsA + i * 4096 + wid * 1024);
      gload_lds16(bptr[i] + kt * 128, (char*)ldsB + i * 4096 + wid * 1024);
    }
    __syncthreads();                           // compiler drains vmcnt
    #pragma unroll
    for (int kk = 0; kk < 4; ++kk) {
      bf16x8 a[4], b[4];
      int ko = kk * 32 + (lane >> 4) * 8;
      #pragma unroll
      for (int m = 0; m < 4; m++) {
        int ra = wr * 64 + m * 16 + (lane & 15);
        a[m] = *(const bf16x8*)&ldsA[ra * 128 + (ko ^ ((ra & 7) << 3))];
      }
      #pragma unroll
      for (int n = 0; n < 4; n++) {
        int rb = wc * 64 + n * 16 + (lane & 15);
        b[n] = *(const bf16x8*)&ldsB[rb * 128 + (ko ^ ((rb & 7) << 3))];
      }
      #pragma unroll
      for (int m = 0; m < 4; m++)
        #pragma unroll
        for (int n = 0; n < 4; n++)
          acc[m][n] = __builtin_amdgcn_mfma_f32_16x16x32_bf16(a[m], b[n], acc[m][n], 0, 0, 0);
    }
    __syncthreads();
  }

  // epilogue: C/D mapping col=lane&15, row=(lane>>4)*4+reg (m89-verified)
  #pragma unroll
  for (int m = 0; m < 4; m++) {
    int rbase = wr * 64 + m * 16 + (lane >> 4) * 4;
    int ent[4];
    #pragma unroll
    for (int r = 0; r < 4; r++) ent[r] = ldsE[rbase + r];
    #pragma unroll
    for (int n = 0; n < 4; n++) {
      int col = ct * 128 + wc * 64 + n * 16 + (lane & 15);
      float bv = (KSPLIT == 1 || ks == 0) ? bias[e * NDIM + col] : 0.f;
      #pragma unroll
      for (int r = 0; r < 4; r++) {
        if (rt * 128 + rbase + r >= cnt) continue;
        float v = acc[m][n][r] + bv;
        if (IS_L1) {
          Hout[(size_t)ent[r] * NDIM + col] = f2bf(gelu_fast(v));
        } else {
          atomicAdd(Out + (size_t)(ent[r] >> 1) * NDIM + col, v * wgtA[ent[r]]);
        }
      }
    }
  }
}

extern "C" void kernel_launch(void* const* d_in, const int* in_sizes, int n_in,
                              void* d_out, int out_size, void* d_ws, size_t ws_size,
                              hipStream_t stream) {
  const float* inp = (const float*)d_in[0];
  const float* gw  = (const float*)d_in[1];
  const float* gb  = (const float*)d_in[2];
  const float* w1  = (const float*)d_in[3];
  const float* b1  = (const float*)d_in[4];
  const float* w2  = (const float*)d_in[5];
  const float* b2  = (const float*)d_in[6];
  float* out = (float*)d_out;

  char* ws = (char*)d_ws;
  unsigned short* Xb   = (unsigned short*)(ws + 0);          //  4 MiB: [4096][512] bf16
  unsigned short* W1T  = (unsigned short*)(ws + 4194304);    // 16 MiB: [8][2048][512] bf16
  unsigned short* W2T  = (unsigned short*)(ws + 20971520);   // 16 MiB: [8][512][2048] bf16
  unsigned short* Hbuf = (unsigned short*)(ws + 37748736);   // 32 MiB: [8192][2048] bf16
  int*   lists  = (int*)  (ws + 71303168);                   // [8][4096] int
  float* wgtA   = (float*)(ws + 71434240);                   // [8192] f32
  int*   counts = (int*)  (ws + 71467008);                   // [8] int
  int*   eidx   = (int*)  (ws + 71467072);                   // [8192] int

  hipMemsetAsync(out, 0, (size_t)NTOK * DM * sizeof(float), stream);

  // fused prep: 1024 convx + 8192 transw1 + 8192 transw2 + 1024 gate
  prep_kernel<<<18432, 256, 0, stream>>>(inp, w1, w2, gw, gb,
                                         Xb, W1T, W2T, eidx, wgtA);
  build_lists<<<NE, 256, 0, stream>>>(eidx, lists, counts);
  // L1: KSPLIT=1, grid 8 x 32rt x 16ct (dead tiles exit on counts)
  moe_gemm<DM, HD, true, 1><<<8 * 32 * 1 * (HD / 128), 256, 0, stream>>>(
      Xb, W1T, b1, lists, counts, wgtA, Hbuf, nullptr);
  // L2: KSPLIT=4, grid 8 x 32rt x 4ks x 4ct -> 4x active blocks, 4 K-steps each
  moe_gemm<HD, DM, false, 4><<<8 * 32 * 4 * (DM / 128), 256, 0, stream>>>(
      Hbuf, W2T, b2, lists, counts, wgtA, nullptr, out);
}